// Round 1
// baseline (814.341 us; speedup 1.0000x reference)
//
#include <hip/hip_runtime.h>
#include <stdint.h>

// CRF loss (forward partition + gold path score), B=32, L=1024, D=1024, 66 tags.
// Phase 1: feats[b,l,c] = features[b,l,:]·fc_w[:,c] + fc_b[c]  (c in [0,64) only --
//          START/STOP emissions are never used: their transitions are -10000 and
//          underflow to exactly 0 in f32, same as in the reference).
// Phase 2: forward scan in the PROBABILITY domain, one wave per batch, lane=tag.
// Phase 3: gold score = sum of gathered transition+emission terms.

#define NTAGS 66
#define START_IDX 64
#define STOP_IDX 65
#define LN2F 0.69314718055994530942f

// ------------------------------------------------------------------
// DPP helpers (full-wave reduce; result valid in lane 63; values >= 0)
// ------------------------------------------------------------------
template <int CTRL>
__device__ __forceinline__ float dpp_mov(float v) {
  return __int_as_float(
      __builtin_amdgcn_update_dpp(0, __float_as_int(v), CTRL, 0xF, 0xF, true));
}
__device__ __forceinline__ float wave_max64(float v) {
  v = fmaxf(v, dpp_mov<0xB1>(v));   // quad_perm xor1
  v = fmaxf(v, dpp_mov<0x4E>(v));   // quad_perm xor2
  v = fmaxf(v, dpp_mov<0x141>(v));  // row_half_mirror
  v = fmaxf(v, dpp_mov<0x140>(v));  // row_mirror
  v = fmaxf(v, dpp_mov<0x142>(v));  // row_bcast15
  v = fmaxf(v, dpp_mov<0x143>(v));  // row_bcast31
  return v;                          // lane 63 has max (non-neg values)
}
__device__ __forceinline__ float wave_sum64(float v) {
  v += dpp_mov<0xB1>(v);
  v += dpp_mov<0x4E>(v);
  v += dpp_mov<0x141>(v);
  v += dpp_mov<0x140>(v);
  v += dpp_mov<0x142>(v);
  v += dpp_mov<0x143>(v);
  return v;                          // lane 63 has sum
}

// ------------------------------------------------------------------
// Phase 1: emission GEMM. A=[32768][1024], W=[1024][66], out=[32768][64].
// 64-row tile per block, K-chunks of 128, 4x4 register blocking per thread.
// ------------------------------------------------------------------
__global__ __launch_bounds__(256) void crf_gemm(const float* __restrict__ A,
                                                const float* __restrict__ W,
                                                const float* __restrict__ bias,
                                                float* __restrict__ out) {
  __shared__ float As[64][132];   // +4 pad breaks bank aliasing on row reads
  __shared__ float Ws[128][64];
  const int tid = threadIdx.x;
  const int m0 = blockIdx.x * 64;
  const int cg = tid & 15;   // cols 4*cg..+4
  const int rg = tid >> 4;   // rows 4*rg..+4
  float acc[4][4];
#pragma unroll
  for (int i = 0; i < 4; ++i)
#pragma unroll
    for (int j = 0; j < 4; ++j) acc[i][j] = 0.f;

  for (int k0 = 0; k0 < 1024; k0 += 128) {
    {
      const int r = tid >> 5;    // 0..7
      const int f4 = tid & 31;   // 0..31
#pragma unroll
      for (int p = 0; p < 8; ++p) {
        float4 v = *(const float4*)(A + (size_t)(m0 + p * 8 + r) * 1024 + k0 + f4 * 4);
        *(float4*)&As[p * 8 + r][f4 * 4] = v;
      }
      const int kk = tid >> 5;   // 0..7
      const int f2 = tid & 31;   // 0..31  (cols 2*f2..+2, only first 64 of 66)
#pragma unroll
      for (int p = 0; p < 16; ++p) {
        float2 v = *(const float2*)(W + (size_t)(k0 + p * 8 + kk) * 66 + f2 * 2);
        *(float2*)&Ws[p * 8 + kk][f2 * 2] = v;
      }
    }
    __syncthreads();
#pragma unroll
    for (int k = 0; k < 128; k += 4) {
      float4 a[4], w[4];
#pragma unroll
      for (int r = 0; r < 4; ++r) a[r] = *(const float4*)&As[rg * 4 + r][k];
#pragma unroll
      for (int kk = 0; kk < 4; ++kk) w[kk] = *(const float4*)&Ws[k + kk][cg * 4];
#pragma unroll
      for (int kk = 0; kk < 4; ++kk) {
#pragma unroll
        for (int r = 0; r < 4; ++r) {
          const float av = (&a[r].x)[kk];
          acc[r][0] = fmaf(av, w[kk].x, acc[r][0]);
          acc[r][1] = fmaf(av, w[kk].y, acc[r][1]);
          acc[r][2] = fmaf(av, w[kk].z, acc[r][2]);
          acc[r][3] = fmaf(av, w[kk].w, acc[r][3]);
        }
      }
    }
    __syncthreads();
  }
  const float4 bv = *(const float4*)(bias + cg * 4);
#pragma unroll
  for (int r = 0; r < 4; ++r) {
    float4 o;
    o.x = acc[r][0] + bv.x;
    o.y = acc[r][1] + bv.y;
    o.z = acc[r][2] + bv.z;
    o.w = acc[r][3] + bv.w;
    *(float4*)(out + (size_t)(m0 + rg * 4 + r) * 64 + cg * 4) = o;
  }
}

// ------------------------------------------------------------------
// Phase 2: forward scan, prob domain. 1 wave per batch, lane = tag.
// State: r_i = p_i (prob rel. to running power-of-2 scale), e_acc = log2(scale).
// Step:  q_i = sum_j p_j * E[i][j];  r_i' = q_i * 2^-ex * exp(emit_i);
//        ex = exponent(max_j p_j) (computed off the critical path).
// ------------------------------------------------------------------
__global__ void crf_scan(const float* __restrict__ fw,     // [32][1024][64]
                         const float* __restrict__ trans,  // [66][66]
                         const float* __restrict__ masks,  // [32][1024]
                         float* __restrict__ out) {
  __shared__ alignas(16) float p_lds[64];
  const int lane = threadIdx.x;
  const int b = blockIdx.x;

  float E[64];
#pragma unroll
  for (int j = 0; j < 64; ++j) E[j] = __expf(trans[lane * 66 + j]);
  const float Est = __expf(trans[lane * 66 + START_IDX]);   // exp(T[i][START])
  const float Efin = __expf(trans[STOP_IDX * 66 + lane]);   // exp(T[STOP][i])

  const float* fb = fw + (size_t)b * (1024 * 64);
  const float* mb = masks + b * 1024;

  float r = 0.f;
  int e_acc = 0;
  bool started = false;

  // software prefetch ring, depth 2 (emission row + mask)
  float e0 = fb[lane], e1 = fb[64 + lane];
  float mk0 = mb[0], mk1 = mb[1];

  for (int t = 0; t < 1024; ++t) {
    const int tn = (t + 2 < 1024) ? (t + 2) : 1023;
    float e2 = fb[tn * 64 + lane];
    float mk2 = mb[tn];

    if (mk0 != 0.0f) {
      const float eem = __expf(e0);   // off critical path (no state dep)
      if (!started) {
        r = eem * Est;                // s_1[i] = emit_1[i] + T[i][START], exact
        started = true;
      } else {
        // ---- off-path: power-of-2 rescale factor from CURRENT state ----
        float mx = wave_max64(r);
        int mxb = __builtin_amdgcn_readlane(__float_as_int(mx), 63);
        int ex = ((mxb >> 23) & 0xFF) - 127;
        float s = eem * __int_as_float((127 - ex) << 23);   // exp(emit)*2^-ex
        e_acc += ex;
        // ---- on-path: broadcast matvec in prob domain ----
        p_lds[lane] = r;
        __builtin_amdgcn_wave_barrier();
        float q0 = 0.f, q1 = 0.f, q2 = 0.f, q3 = 0.f;
        const float4* p4 = (const float4*)p_lds;
#pragma unroll
        for (int j4 = 0; j4 < 16; ++j4) {
          float4 pv = p4[j4];   // broadcast read, conflict-free
          q0 = fmaf(pv.x, E[4 * j4 + 0], q0);
          q1 = fmaf(pv.y, E[4 * j4 + 1], q1);
          q2 = fmaf(pv.z, E[4 * j4 + 2], q2);
          q3 = fmaf(pv.w, E[4 * j4 + 3], q3);
        }
        r = ((q0 + q1) + (q2 + q3)) * s;
      }
    }
    e0 = e1; e1 = e2; mk0 = mk1; mk1 = mk2;
  }

  float fwdv;
  if (!started) {
    fwdv = trans[STOP_IDX * 66 + START_IDX];
  } else {
    float sum = wave_sum64(r * Efin);
    int sb = __builtin_amdgcn_readlane(__float_as_int(sum), 63);
    fwdv = __logf(__int_as_float(sb)) + (float)e_acc * LN2F;
  }
  if (lane == 0) out[b] = fwdv;
}

// ------------------------------------------------------------------
// Phase 3: gold path score. 1 wave per batch.
// ------------------------------------------------------------------
__global__ void crf_gold(const float* __restrict__ fw,     // [32][1024][64]
                         const int* __restrict__ ys,       // [32][1024]
                         const float* __restrict__ masks,  // [32][1024]
                         const float* __restrict__ trans,  // [66][66]
                         float* __restrict__ out) {
  const int lane = threadIdx.x;
  const int b = blockIdx.x;
  const float* fb = fw + (size_t)b * (1024 * 64);
  const float* mb = masks + b * 1024;
  const int* yb = ys + b * 1024;
  float s = 0.f, cnt = 0.f;
#pragma unroll
  for (int c = 0; c < 16; ++c) {
    const int t = c * 64 + lane;
    const float m = mb[t];
    const int y = yb[t];
    const int yp = (t == 0) ? START_IDX : yb[t - 1];
    s += (trans[y * 66 + yp] + fb[t * 64 + y]) * m;
    cnt += m;
  }
  float tot = wave_sum64(s);
  float len = wave_sum64(cnt);
  int totb = __builtin_amdgcn_readlane(__float_as_int(tot), 63);
  int lenb = __builtin_amdgcn_readlane(__float_as_int(len), 63);
  if (lane == 0) {
    const int Lr = (int)__int_as_float(lenb);
    const int last = (Lr == 0) ? START_IDX : yb[Lr - 1];
    out[32 + b] = __int_as_float(totb) + trans[STOP_IDX * 66 + last];
  }
}

// ------------------------------------------------------------------
extern "C" void kernel_launch(void* const* d_in, const int* in_sizes, int n_in,
                              void* d_out, int out_size, void* d_ws, size_t ws_size,
                              hipStream_t stream) {
  const float* features = (const float*)d_in[0];   // [32][1024][1024]
  const int* ys         = (const int*)d_in[1];     // [32][1024]
  const float* masks    = (const float*)d_in[2];   // [32][1024]
  const float* fc_w     = (const float*)d_in[3];   // [1024][66]
  const float* fc_b     = (const float*)d_in[4];   // [66]
  const float* trans    = (const float*)d_in[5];   // [66][66]
  float* outp = (float*)d_out;                     // [0..31]=forward, [32..63]=gold
  float* feats_ws = (float*)d_ws;                  // 32*1024*64 f32 = 8.39 MB

  crf_gemm<<<512, 256, 0, stream>>>(features, fc_w, fc_b, feats_ws);
  crf_scan<<<32, 64, 0, stream>>>(feats_ws, trans, masks, outp);
  crf_gold<<<32, 64, 0, stream>>>(feats_ws, ys, masks, trans, outp);
}

// Round 2
// 304.784 us; speedup vs baseline: 2.6719x; 2.6719x over previous
//
#include <hip/hip_runtime.h>
#include <hip/hip_bf16.h>
#include <stdint.h>

// CRF loss (forward partition + gold path score), B=32, L=1024, D=1024, 66 tags.
// Pipeline:
//   crf_wcvt   : fc_w [1024][66] fp32 -> Wbt [64][1024] bf16 (transposed)
//   crf_mm     : feats = features . fc_w + b  via bf16 MFMA, out fp32 [32768][64]
//   crf_chunks : per (batch, 64-step chunk) product of M_t = diag(exp(emit_t)).E
//                as 64x64 bf16 MFMA matmuls with per-step pow2 rescale
//   crf_combine: per batch, apply 16 chunk matrices to init vector (matvec),
//                final logsumexp with STOP transitions
//   crf_gold   : gold path score (gathers)
//
// START/STOP tags are exactly representable as prob-0 (exp(-10000) underflows
// to 0 in f32, same as the reference) -> live state is exactly 64 tags.

#define START_IDX 64
#define STOP_IDX 65
#define LN2F 0.6931471805599453f

typedef __attribute__((ext_vector_type(4))) float f32x4;
typedef __attribute__((ext_vector_type(8))) __bf16 bf16x8;
typedef __attribute__((ext_vector_type(4))) __bf16 bf16x4;

// ------------------------------------------------------------------
// DPP helpers (full-wave reduce; result valid in lane 63; values >= 0)
// ------------------------------------------------------------------
template <int CTRL>
__device__ __forceinline__ float dpp_mov(float v) {
  return __int_as_float(
      __builtin_amdgcn_update_dpp(0, __float_as_int(v), CTRL, 0xF, 0xF, true));
}
__device__ __forceinline__ float wave_max64(float v) {
  v = fmaxf(v, dpp_mov<0xB1>(v));   // quad_perm xor1
  v = fmaxf(v, dpp_mov<0x4E>(v));   // quad_perm xor2
  v = fmaxf(v, dpp_mov<0x141>(v));  // row_half_mirror
  v = fmaxf(v, dpp_mov<0x140>(v));  // row_mirror
  v = fmaxf(v, dpp_mov<0x142>(v));  // row_bcast15
  v = fmaxf(v, dpp_mov<0x143>(v));  // row_bcast31
  return v;
}
__device__ __forceinline__ float wave_sum64(float v) {
  v += dpp_mov<0xB1>(v);
  v += dpp_mov<0x4E>(v);
  v += dpp_mov<0x141>(v);
  v += dpp_mov<0x140>(v);
  v += dpp_mov<0x142>(v);
  v += dpp_mov<0x143>(v);
  return v;
}

// ------------------------------------------------------------------
// W convert+transpose: Wbt[n][k] = bf16(W[k][n]), n<64, k<1024
// ------------------------------------------------------------------
__global__ void crf_wcvt(const float* __restrict__ W,
                         unsigned short* __restrict__ Wbt) {
  const int idx = blockIdx.x * 256 + threadIdx.x;  // 65536 total
  const int n = idx >> 10, k = idx & 1023;
  union { __bf16 h; unsigned short u; } cv;
  cv.h = (__bf16)W[k * 66 + n];
  Wbt[idx] = cv.u;
}

// ------------------------------------------------------------------
// Emission GEMM via MFMA. M=32768 N=64 K=1024.
// Block = 4 waves, each wave owns 16 rows x 64 cols. A fp32->bf16 in reg,
// B preconverted bf16 row-major [n][k] so B-frags are contiguous 16B loads.
// ------------------------------------------------------------------
__global__ __launch_bounds__(256) void crf_mm(const float* __restrict__ A,
                                              const unsigned short* __restrict__ Wbt,
                                              const float* __restrict__ bias,
                                              float* __restrict__ out) {
  const int tid = threadIdx.x;
  const int w = tid >> 6, lane = tid & 63, g = lane >> 4, q = lane & 15;
  const int m0 = blockIdx.x * 64 + 16 * w;

  const float* Arow = A + (size_t)(m0 + q) * 1024 + 8 * g;
  const unsigned short* Bp0 = Wbt + (q + 0) * 1024 + 8 * g;
  const unsigned short* Bp1 = Wbt + (q + 16) * 1024 + 8 * g;
  const unsigned short* Bp2 = Wbt + (q + 32) * 1024 + 8 * g;
  const unsigned short* Bp3 = Wbt + (q + 48) * 1024 + 8 * g;

  f32x4 acc0 = {0.f, 0.f, 0.f, 0.f}, acc1 = acc0, acc2 = acc0, acc3 = acc0;

#pragma unroll
  for (int k0 = 0; k0 < 1024; k0 += 32) {
    float4 a0 = *(const float4*)(Arow + k0);
    float4 a1 = *(const float4*)(Arow + k0 + 4);
    bf16x8 af;
    af[0] = (__bf16)a0.x; af[1] = (__bf16)a0.y; af[2] = (__bf16)a0.z; af[3] = (__bf16)a0.w;
    af[4] = (__bf16)a1.x; af[5] = (__bf16)a1.y; af[6] = (__bf16)a1.z; af[7] = (__bf16)a1.w;
    bf16x8 b0 = *(const bf16x8*)(Bp0 + k0);
    bf16x8 b1 = *(const bf16x8*)(Bp1 + k0);
    bf16x8 b2 = *(const bf16x8*)(Bp2 + k0);
    bf16x8 b3 = *(const bf16x8*)(Bp3 + k0);
    acc0 = __builtin_amdgcn_mfma_f32_16x16x32_bf16(af, b0, acc0, 0, 0, 0);
    acc1 = __builtin_amdgcn_mfma_f32_16x16x32_bf16(af, b1, acc1, 0, 0, 0);
    acc2 = __builtin_amdgcn_mfma_f32_16x16x32_bf16(af, b2, acc2, 0, 0, 0);
    acc3 = __builtin_amdgcn_mfma_f32_16x16x32_bf16(af, b3, acc3, 0, 0, 0);
  }

  const float bb0 = bias[q + 0], bb1 = bias[q + 16];
  const float bb2 = bias[q + 32], bb3 = bias[q + 48];
#pragma unroll
  for (int r = 0; r < 4; ++r) {
    float* orow = out + (size_t)(m0 + 4 * g + r) * 64 + q;
    orow[0]  = acc0[r] + bb0;
    orow[16] = acc1[r] + bb1;
    orow[32] = acc2[r] + bb2;
    orow[48] = acc3[r] + bb3;
  }
}

// ------------------------------------------------------------------
// Chunk product kernel. Grid (16 chunks, 32 batches), 4 waves.
// LDS T[buf][n][k] = P^T bf16, XOR-swizzled: byte ^= (n&7)<<4  (b128 reads
// conflict-free). Per step: C = E.P (8 MFMA), row-scale by exp(emit)*2^-ex,
// (ex from 1-step-lagged global max), cvt bf16, write other buffer, 1 barrier.
// ------------------------------------------------------------------
__global__ __launch_bounds__(256) void crf_chunks(const float* __restrict__ feats,
                                                  const float* __restrict__ masks,
                                                  const float* __restrict__ trans,
                                                  float* __restrict__ chunkP,
                                                  int* __restrict__ chunkExp) {
  __shared__ __align__(16) unsigned short T[2][4096];
  __shared__ float wmax[2][4];
  const int tid = threadIdx.x;
  const int w = tid >> 6, lane = tid & 63, g = lane >> 4, q = lane & 15;
  const int c = blockIdx.x, b = blockIdx.y;
  const int t0 = (c == 0) ? 1 : (c << 6);
  const int t1 = (c << 6) + 64;

  // E fragments (A operand): rows i = 16w+q, k = 32*kh + 8*g + e
  bf16x8 Ea0, Ea1;
  {
    const int i = 16 * w + q;
    const float* tp0 = trans + i * 66 + 8 * g;
    const float* tp1 = tp0 + 32;
#pragma unroll
    for (int e = 0; e < 8; ++e) {
      Ea0[e] = (__bf16)__expf(tp0[e]);
      Ea1[e] = (__bf16)__expf(tp1[e]);
    }
  }

  // buffer 0 = identity (swizzled)
  for (int idx = tid; idx < 4096; idx += 256) {
    const int n = idx >> 6, mm = idx & 63;
    const int off = n * 128 + ((2 * mm) ^ ((n & 7) << 4));
    *(unsigned short*)((char*)T[0] + off) =
        (n == mm) ? (unsigned short)0x3F80 : (unsigned short)0;
  }
  if (tid < 4) wmax[0][tid] = 1.0f;

  float pv[4][4];  // C-layout copy of current P (fp32): row 16w+4g+r, col q+16nt
#pragma unroll
  for (int nt = 0; nt < 4; ++nt)
#pragma unroll
    for (int r = 0; r < 4; ++r)
      pv[nt][r] = ((16 * w + 4 * g + r) == (q + 16 * nt)) ? 1.f : 0.f;

  const float* fb = feats + ((size_t)b << 16);
  const float* mb = masks + (b << 10);
  const int tml = t0 + lane;
  const float mkv = mb[tml > 1023 ? 1023 : tml];

  int e_acc = 0;
  int cur = 0;
  __syncthreads();

  // emission prefetch ring (depth 2)
  const int ecol = 16 * w + 4 * g;
  float4 fa = *(const float4*)(fb + t0 * 64 + ecol);
  int tpre = t0 + 1; if (tpre > 1023) tpre = 1023;
  float4 fbv = *(const float4*)(fb + tpre * 64 + ecol);

  for (int t = t0; t < t1; ++t) {
    int tn = t + 2; if (tn > 1023) tn = 1023;
    float4 fnext = *(const float4*)(fb + tn * 64 + ecol);
    float4 fcur = fa; fa = fbv; fbv = fnext;
    const float m =
        __int_as_float(__builtin_amdgcn_readlane(__float_as_int(mkv), t - t0));
    if (m != 0.f) {
      const char* Tb = (const char*)T[cur];
      f32x4 acc[4];
#pragma unroll
      for (int nt = 0; nt < 4; ++nt) {
        const int n = q + 16 * nt;
        const int sw = (n & 7) << 4;
        bf16x8 B0 = *(const bf16x8*)(Tb + n * 128 + ((16 * g) ^ sw));
        bf16x8 B1 = *(const bf16x8*)(Tb + n * 128 + ((64 + 16 * g) ^ sw));
        f32x4 z = {0.f, 0.f, 0.f, 0.f};
        z = __builtin_amdgcn_mfma_f32_16x16x32_bf16(Ea0, B0, z, 0, 0, 0);
        acc[nt] = __builtin_amdgcn_mfma_f32_16x16x32_bf16(Ea1, B1, acc[nt] = z, 0, 0, 0);
      }
      const float4 wm = *(const float4*)wmax[cur];
      const float mx = fmaxf(fmaxf(wm.x, wm.y), fmaxf(wm.z, wm.w));
      const int ex = ((__float_as_int(mx) >> 23) & 0xFF) - 127;
      const float sc = __int_as_float((127 - ex) << 23);
      float ce[4];
      ce[0] = __expf(fcur.x) * sc; ce[1] = __expf(fcur.y) * sc;
      ce[2] = __expf(fcur.z) * sc; ce[3] = __expf(fcur.w) * sc;
      float lm = 0.f;
#pragma unroll
      for (int nt = 0; nt < 4; ++nt) {
#pragma unroll
        for (int r = 0; r < 4; ++r) {
          float val = acc[nt][r] * ce[r];
          if (m != 1.f) val = m * val + (1.f - m) * sc * pv[nt][r];
          pv[nt][r] = val;
          lm = fmaxf(lm, val);
        }
      }
      lm = wave_max64(lm);
      const int nxt = cur ^ 1;
      char* Tw = (char*)T[nxt];
#pragma unroll
      for (int nt = 0; nt < 4; ++nt) {
        bf16x4 o;
        o[0] = (__bf16)pv[nt][0]; o[1] = (__bf16)pv[nt][1];
        o[2] = (__bf16)pv[nt][2]; o[3] = (__bf16)pv[nt][3];
        const int n = q + 16 * nt;
        *(bf16x4*)(Tw + n * 128 + ((32 * w + 8 * g) ^ ((n & 7) << 4))) = o;
      }
      if (lane == 63) wmax[nxt][w] = lm;
      e_acc += ex;
      __syncthreads();
      cur = nxt;
    }
  }

  // epilogue: write P (fp32) + exponent
#pragma unroll
  for (int nt = 0; nt < 4; ++nt)
#pragma unroll
    for (int r = 0; r < 4; ++r)
      chunkP[(((size_t)(b * 16 + c)) << 12) + (size_t)(16 * w + 4 * g + r) * 64 +
             q + 16 * nt] = pv[nt][r];
  if (tid == 0) chunkExp[b * 16 + c] = e_acc;
}

// ------------------------------------------------------------------
// Combine: per batch, v <- Pc . v over 16 chunks, then STOP logsumexp.
// ------------------------------------------------------------------
__global__ void crf_combine(const float* __restrict__ feats,
                            const float* __restrict__ trans,
                            const float* __restrict__ chunkP,
                            const int* __restrict__ chunkExp,
                            float* __restrict__ out) {
  __shared__ __align__(16) float vb[64];
  const int lane = threadIdx.x;
  const int b = blockIdx.x;
  // t=0 init: v[i] = exp(emit_0[i]) * exp(T[i][START])   (mask[b][0]==1)
  float v = __expf(feats[((size_t)b << 16) + lane]) *
            __expf(trans[lane * 66 + START_IDX]);
  int e_acc = 0;
  for (int c = 0; c < 16; ++c) {
    vb[lane] = v;
    __builtin_amdgcn_wave_barrier();
    const float* Pr = chunkP + (((size_t)(b * 16 + c)) << 12) + (size_t)lane * 64;
    float q0 = 0.f, q1 = 0.f, q2 = 0.f, q3 = 0.f;
#pragma unroll
    for (int j4 = 0; j4 < 16; ++j4) {
      float4 p = *(const float4*)(Pr + 4 * j4);
      float4 x = ((const float4*)vb)[j4];
      q0 = fmaf(p.x, x.x, q0); q1 = fmaf(p.y, x.y, q1);
      q2 = fmaf(p.z, x.z, q2); q3 = fmaf(p.w, x.w, q3);
    }
    const float qq = (q0 + q1) + (q2 + q3);
    float mx = wave_max64(qq);
    mx = __int_as_float(__builtin_amdgcn_readlane(__float_as_int(mx), 63));
    const int ex = ((__float_as_int(mx) >> 23) & 0xFF) - 127;
    v = qq * __int_as_float((127 - ex) << 23);
    e_acc += ex + chunkExp[b * 16 + c];
    __builtin_amdgcn_wave_barrier();
  }
  const float sum = wave_sum64(v * __expf(trans[STOP_IDX * 66 + lane]));
  const float s = __int_as_float(__builtin_amdgcn_readlane(__float_as_int(sum), 63));
  if (lane == 0) out[b] = __logf(s) + (float)e_acc * LN2F;
}

// ------------------------------------------------------------------
// Gold path score. 1 wave per batch.
// ------------------------------------------------------------------
__global__ void crf_gold(const float* __restrict__ fw,
                         const int* __restrict__ ys,
                         const float* __restrict__ masks,
                         const float* __restrict__ trans,
                         float* __restrict__ out) {
  const int lane = threadIdx.x;
  const int b = blockIdx.x;
  const float* fb = fw + (size_t)b * (1024 * 64);
  const float* mb = masks + b * 1024;
  const int* yb = ys + b * 1024;
  float s = 0.f, cnt = 0.f;
#pragma unroll
  for (int c = 0; c < 16; ++c) {
    const int t = c * 64 + lane;
    const float m = mb[t];
    const int y = yb[t];
    const int yp = (t == 0) ? START_IDX : yb[t - 1];
    s += (trans[y * 66 + yp] + fb[t * 64 + y]) * m;
    cnt += m;
  }
  float tot = wave_sum64(s);
  float len = wave_sum64(cnt);
  int totb = __builtin_amdgcn_readlane(__float_as_int(tot), 63);
  int lenb = __builtin_amdgcn_readlane(__float_as_int(len), 63);
  if (lane == 0) {
    const int Lr = (int)__int_as_float(lenb);
    const int last = (Lr == 0) ? START_IDX : yb[Lr - 1];
    out[32 + b] = __int_as_float(totb) + trans[STOP_IDX * 66 + last];
  }
}

// ------------------------------------------------------------------
extern "C" void kernel_launch(void* const* d_in, const int* in_sizes, int n_in,
                              void* d_out, int out_size, void* d_ws, size_t ws_size,
                              hipStream_t stream) {
  const float* features = (const float*)d_in[0];   // [32][1024][1024]
  const int* ys         = (const int*)d_in[1];     // [32][1024]
  const float* masks    = (const float*)d_in[2];   // [32][1024]
  const float* fc_w     = (const float*)d_in[3];   // [1024][66]
  const float* fc_b     = (const float*)d_in[4];   // [66]
  const float* trans    = (const float*)d_in[5];   // [66][66]
  float* outp = (float*)d_out;                     // [0..31]=forward, [32..63]=gold

  // workspace layout
  char* ws = (char*)d_ws;
  float* feats_ws = (float*)ws;                                   // 8,388,608 B
  unsigned short* Wbt = (unsigned short*)(ws + 8388608);          //   131,072 B
  float* chunkP = (float*)(ws + 8388608 + 131072);                // 8,388,608 B
  int* chunkExp = (int*)(ws + 8388608 + 131072 + 8388608);        //     2,048 B

  crf_wcvt<<<256, 256, 0, stream>>>(fc_w, Wbt);
  crf_mm<<<512, 256, 0, stream>>>(features, Wbt, fc_b, feats_ws);
  dim3 cg(16, 32);
  crf_chunks<<<cg, 256, 0, stream>>>(feats_ws, masks, trans, chunkP, chunkExp);
  crf_combine<<<32, 64, 0, stream>>>(feats_ws, trans, chunkP, chunkExp, outp);
  crf_gold<<<32, 64, 0, stream>>>(feats_ws, ys, masks, trans, outp);
}

// Round 3
// 285.895 us; speedup vs baseline: 2.8484x; 1.0661x over previous
//
#include <hip/hip_runtime.h>
#include <hip/hip_bf16.h>
#include <stdint.h>

// CRF loss (forward partition + gold path score), B=32, L=1024, D=1024, 66 tags.
// Pipeline (3 kernels):
//   crf_wcvt : fc_w [1024][66] fp32 -> Wbt [64][1024] bf16 (transposed)
//   crf_fwd  : per (chunk c, batch b) block:
//              (a) emission tile GEMM via bf16 MFMA: feats[t0:t0+64][0:64],
//                  raw fp32 -> ws (for gold/combine), exp() -> LDS
//              (b) 64-step chunk product of M_t = diag(exp(emit_t)).E as
//                  64x64 bf16 MFMA matmuls with per-step pow2 rescale
//              -> chunkP (fp32 64x64) + chunkExp per (b,c)
//   crf_fin  : even blocks: per-batch combine (16 chained matvecs + STOP lse)
//              odd blocks:  gold path score (gathers)
//
// START/STOP tags are exact prob-0 (exp(-10000) underflows to 0 in f32, same
// as the reference) -> live state is exactly 64 tags = one wave lane each.

#define START_IDX 64
#define STOP_IDX 65
#define LN2F 0.6931471805599453f

typedef __attribute__((ext_vector_type(4))) float f32x4;
typedef __attribute__((ext_vector_type(8))) __bf16 bf16x8;
typedef __attribute__((ext_vector_type(4))) __bf16 bf16x4;

// ------------------------------------------------------------------
// DPP helpers (full-wave reduce; result valid in lane 63; values >= 0)
// ------------------------------------------------------------------
template <int CTRL>
__device__ __forceinline__ float dpp_mov(float v) {
  return __int_as_float(
      __builtin_amdgcn_update_dpp(0, __float_as_int(v), CTRL, 0xF, 0xF, true));
}
__device__ __forceinline__ float wave_max64(float v) {
  v = fmaxf(v, dpp_mov<0xB1>(v));   // quad_perm xor1
  v = fmaxf(v, dpp_mov<0x4E>(v));   // quad_perm xor2
  v = fmaxf(v, dpp_mov<0x141>(v));  // row_half_mirror
  v = fmaxf(v, dpp_mov<0x140>(v));  // row_mirror
  v = fmaxf(v, dpp_mov<0x142>(v));  // row_bcast15
  v = fmaxf(v, dpp_mov<0x143>(v));  // row_bcast31
  return v;
}
__device__ __forceinline__ float wave_sum64(float v) {
  v += dpp_mov<0xB1>(v);
  v += dpp_mov<0x4E>(v);
  v += dpp_mov<0x141>(v);
  v += dpp_mov<0x140>(v);
  v += dpp_mov<0x142>(v);
  v += dpp_mov<0x143>(v);
  return v;
}

// ------------------------------------------------------------------
// W convert+transpose: Wbt[n][k] = bf16(W[k][n]), n<64, k<1024
// ------------------------------------------------------------------
__global__ void crf_wcvt(const float* __restrict__ W,
                         unsigned short* __restrict__ Wbt) {
  const int idx = blockIdx.x * 256 + threadIdx.x;  // 65536 total
  const int n = idx >> 10, k = idx & 1023;
  union { __bf16 h; unsigned short u; } cv;
  cv.h = (__bf16)W[k * 66 + n];
  Wbt[idx] = cv.u;
}

// ------------------------------------------------------------------
// Fused emission + chunk-product kernel. Grid (16 chunks, 32 batches), 4 waves.
// ------------------------------------------------------------------
__global__ __launch_bounds__(256) void crf_fwd(const float* __restrict__ features,
                                               const unsigned short* __restrict__ Wbt,
                                               const float* __restrict__ bias,
                                               const float* __restrict__ masks,
                                               const float* __restrict__ trans,
                                               float* __restrict__ featsOut,
                                               float* __restrict__ chunkP,
                                               int* __restrict__ chunkExp) {
  __shared__ __align__(16) float expE[64][64];        // exp(emissions) tile
  __shared__ __align__(16) unsigned short T[2][4096]; // P^T bf16, swizzled
  __shared__ float wmax[2][4];
  const int tid = threadIdx.x;
  const int w = tid >> 6, lane = tid & 63, g = lane >> 4, q = lane & 15;
  const int c = blockIdx.x, b = blockIdx.y;

  // ---- T[0] = identity (swizzled), wmax[0] = 1 (independent of GEMM) ----
  for (int idx = tid; idx < 4096; idx += 256) {
    const int n = idx >> 6, mm = idx & 63;
    const int off = n * 128 + ((2 * mm) ^ ((n & 7) << 4));
    *(unsigned short*)((char*)T[0] + off) =
        (n == mm) ? (unsigned short)0x3F80 : (unsigned short)0;
  }
  if (tid < 4) wmax[0][tid] = 1.0f;

  // ---- (a) emission tile GEMM: rows t = c*64 + [0,64), cols = 64 tags ----
  {
    const int trow = (c << 6) + 16 * w + q;  // A-frag row for this lane
    const float* Arow = features + ((size_t)b << 20) + (size_t)trow * 1024 + 8 * g;
    const unsigned short* Bp0 = Wbt + (q + 0) * 1024 + 8 * g;
    const unsigned short* Bp1 = Wbt + (q + 16) * 1024 + 8 * g;
    const unsigned short* Bp2 = Wbt + (q + 32) * 1024 + 8 * g;
    const unsigned short* Bp3 = Wbt + (q + 48) * 1024 + 8 * g;
    f32x4 acc0 = {0.f, 0.f, 0.f, 0.f}, acc1 = acc0, acc2 = acc0, acc3 = acc0;
#pragma unroll
    for (int k0 = 0; k0 < 1024; k0 += 32) {
      float4 a0 = *(const float4*)(Arow + k0);
      float4 a1 = *(const float4*)(Arow + k0 + 4);
      bf16x8 af;
      af[0] = (__bf16)a0.x; af[1] = (__bf16)a0.y; af[2] = (__bf16)a0.z; af[3] = (__bf16)a0.w;
      af[4] = (__bf16)a1.x; af[5] = (__bf16)a1.y; af[6] = (__bf16)a1.z; af[7] = (__bf16)a1.w;
      bf16x8 b0 = *(const bf16x8*)(Bp0 + k0);
      bf16x8 b1 = *(const bf16x8*)(Bp1 + k0);
      bf16x8 b2 = *(const bf16x8*)(Bp2 + k0);
      bf16x8 b3 = *(const bf16x8*)(Bp3 + k0);
      acc0 = __builtin_amdgcn_mfma_f32_16x16x32_bf16(af, b0, acc0, 0, 0, 0);
      acc1 = __builtin_amdgcn_mfma_f32_16x16x32_bf16(af, b1, acc1, 0, 0, 0);
      acc2 = __builtin_amdgcn_mfma_f32_16x16x32_bf16(af, b2, acc2, 0, 0, 0);
      acc3 = __builtin_amdgcn_mfma_f32_16x16x32_bf16(af, b3, acc3, 0, 0, 0);
    }
    const float bb0 = bias[q + 0], bb1 = bias[q + 16];
    const float bb2 = bias[q + 32], bb3 = bias[q + 48];
#pragma unroll
    for (int r = 0; r < 4; ++r) {
      const int tl = 16 * w + 4 * g + r;  // C row (local t)
      float* orow = featsOut + (((size_t)(b << 10) + (c << 6) + tl) << 6) + q;
      const float v0 = acc0[r] + bb0, v1 = acc1[r] + bb1;
      const float v2 = acc2[r] + bb2, v3 = acc3[r] + bb3;
      orow[0] = v0; orow[16] = v1; orow[32] = v2; orow[48] = v3;
      expE[tl][q + 0]  = __expf(v0);
      expE[tl][q + 16] = __expf(v1);
      expE[tl][q + 32] = __expf(v2);
      expE[tl][q + 48] = __expf(v3);
    }
  }

  // ---- (b) chunk scan ----
  // E fragments (A operand): rows i = 16w+q, k = 32*kh + 8*g + e
  bf16x8 Ea0, Ea1;
  {
    const int i = 16 * w + q;
    const float* tp0 = trans + i * 66 + 8 * g;
    const float* tp1 = tp0 + 32;
#pragma unroll
    for (int e = 0; e < 8; ++e) {
      Ea0[e] = (__bf16)__expf(tp0[e]);
      Ea1[e] = (__bf16)__expf(tp1[e]);
    }
  }

  float pv[4][4];  // fp32 copy of P: row 16w+4g+r, col q+16nt
#pragma unroll
  for (int nt = 0; nt < 4; ++nt)
#pragma unroll
    for (int r = 0; r < 4; ++r)
      pv[nt][r] = ((16 * w + 4 * g + r) == (q + 16 * nt)) ? 1.f : 0.f;

  const int t0 = (c == 0) ? 1 : (c << 6);
  const int t1 = (c << 6) + 64;
  const float* mb = masks + (b << 10);
  const int tml = t0 + lane;
  const float mkv = mb[tml > 1023 ? 1023 : tml];

  int e_acc = 0;
  int cur = 0;
  __syncthreads();  // T[0], expE ready

  for (int t = t0; t < t1; ++t) {
    const int tl = t - (c << 6);
    const float4 ee = *(const float4*)&expE[tl][16 * w + 4 * g];  // exp(emit_t)
    const float m =
        __int_as_float(__builtin_amdgcn_readlane(__float_as_int(mkv), t - t0));
    if (m != 0.f) {
      const char* Tb = (const char*)T[cur];
      f32x4 acc[4];
#pragma unroll
      for (int nt = 0; nt < 4; ++nt) {
        const int n = q + 16 * nt;
        const int sw = (n & 7) << 4;
        bf16x8 B0 = *(const bf16x8*)(Tb + n * 128 + ((16 * g) ^ sw));
        bf16x8 B1 = *(const bf16x8*)(Tb + n * 128 + ((64 + 16 * g) ^ sw));
        f32x4 z = {0.f, 0.f, 0.f, 0.f};
        z = __builtin_amdgcn_mfma_f32_16x16x32_bf16(Ea0, B0, z, 0, 0, 0);
        acc[nt] = __builtin_amdgcn_mfma_f32_16x16x32_bf16(Ea1, B1, z, 0, 0, 0);
      }
      const float4 wm = *(const float4*)wmax[cur];
      const float mx = fmaxf(fmaxf(wm.x, wm.y), fmaxf(wm.z, wm.w));
      const int ex = ((__float_as_int(mx) >> 23) & 0xFF) - 127;
      const float sc = __int_as_float((127 - ex) << 23);
      float ce[4];
      ce[0] = ee.x * sc; ce[1] = ee.y * sc; ce[2] = ee.z * sc; ce[3] = ee.w * sc;
      float lm = 0.f;
#pragma unroll
      for (int nt = 0; nt < 4; ++nt) {
#pragma unroll
        for (int r = 0; r < 4; ++r) {
          float val = acc[nt][r] * ce[r];
          if (m != 1.f) val = m * val + (1.f - m) * sc * pv[nt][r];
          pv[nt][r] = val;
          lm = fmaxf(lm, val);
        }
      }
      lm = wave_max64(lm);
      const int nxt = cur ^ 1;
      char* Tw = (char*)T[nxt];
#pragma unroll
      for (int nt = 0; nt < 4; ++nt) {
        bf16x4 o;
        o[0] = (__bf16)pv[nt][0]; o[1] = (__bf16)pv[nt][1];
        o[2] = (__bf16)pv[nt][2]; o[3] = (__bf16)pv[nt][3];
        const int n = q + 16 * nt;
        *(bf16x4*)(Tw + n * 128 + ((32 * w + 8 * g) ^ ((n & 7) << 4))) = o;
      }
      if (lane == 63) wmax[nxt][w] = lm;
      e_acc += ex;
      __syncthreads();
      cur = nxt;
    }
  }

  // epilogue: write P (fp32) + exponent
#pragma unroll
  for (int nt = 0; nt < 4; ++nt)
#pragma unroll
    for (int r = 0; r < 4; ++r)
      chunkP[(((size_t)(b * 16 + c)) << 12) + (size_t)(16 * w + 4 * g + r) * 64 +
             q + 16 * nt] = pv[nt][r];
  if (tid == 0) chunkExp[b * 16 + c] = e_acc;
}

// ------------------------------------------------------------------
// Final kernel: even blocks -> combine (forward score), odd -> gold score.
// ------------------------------------------------------------------
__global__ void crf_fin(const float* __restrict__ feats,
                        const int* __restrict__ ys,
                        const float* __restrict__ masks,
                        const float* __restrict__ trans,
                        const float* __restrict__ chunkP,
                        const int* __restrict__ chunkExp,
                        float* __restrict__ out) {
  __shared__ __align__(16) float vb[64];
  const int lane = threadIdx.x;
  const int b = blockIdx.x >> 1;
  if ((blockIdx.x & 1) == 0) {
    // ---- combine: v <- Pc . v over 16 chunks, then STOP logsumexp ----
    float v = __expf(feats[((size_t)b << 16) + lane]) *
              __expf(trans[lane * 66 + START_IDX]);
    int e_acc = 0;
    for (int cc = 0; cc < 16; ++cc) {
      vb[lane] = v;
      __builtin_amdgcn_wave_barrier();
      const float* Pr = chunkP + (((size_t)(b * 16 + cc)) << 12) + (size_t)lane * 64;
      float q0 = 0.f, q1 = 0.f, q2 = 0.f, q3 = 0.f;
#pragma unroll
      for (int j4 = 0; j4 < 16; ++j4) {
        float4 p = *(const float4*)(Pr + 4 * j4);
        float4 x = ((const float4*)vb)[j4];
        q0 = fmaf(p.x, x.x, q0); q1 = fmaf(p.y, x.y, q1);
        q2 = fmaf(p.z, x.z, q2); q3 = fmaf(p.w, x.w, q3);
      }
      const float qq = (q0 + q1) + (q2 + q3);
      float mx = wave_max64(qq);
      mx = __int_as_float(__builtin_amdgcn_readlane(__float_as_int(mx), 63));
      const int ex = ((__float_as_int(mx) >> 23) & 0xFF) - 127;
      v = qq * __int_as_float((127 - ex) << 23);
      e_acc += ex + chunkExp[b * 16 + cc];
      __builtin_amdgcn_wave_barrier();
    }
    const float sum = wave_sum64(v * __expf(trans[STOP_IDX * 66 + lane]));
    const float s =
        __int_as_float(__builtin_amdgcn_readlane(__float_as_int(sum), 63));
    if (lane == 0) out[b] = __logf(s) + (float)e_acc * LN2F;
  } else {
    // ---- gold path score ----
    const float* fb = feats + ((size_t)b << 16);
    const float* mb = masks + (b << 10);
    const int* yb = ys + (b << 10);
    float s = 0.f, cnt = 0.f;
#pragma unroll
    for (int cc = 0; cc < 16; ++cc) {
      const int t = cc * 64 + lane;
      const float m = mb[t];
      const int y = yb[t];
      const int yp = (t == 0) ? START_IDX : yb[t - 1];
      s += (trans[y * 66 + yp] + fb[t * 64 + y]) * m;
      cnt += m;
    }
    float tot = wave_sum64(s);
    float len = wave_sum64(cnt);
    int totb = __builtin_amdgcn_readlane(__float_as_int(tot), 63);
    int lenb = __builtin_amdgcn_readlane(__float_as_int(len), 63);
    if (lane == 0) {
      const int Lr = (int)__int_as_float(lenb);
      const int last = (Lr == 0) ? START_IDX : yb[Lr - 1];
      out[32 + b] = __int_as_float(totb) + trans[STOP_IDX * 66 + last];
    }
  }
}

// ------------------------------------------------------------------
extern "C" void kernel_launch(void* const* d_in, const int* in_sizes, int n_in,
                              void* d_out, int out_size, void* d_ws, size_t ws_size,
                              hipStream_t stream) {
  const float* features = (const float*)d_in[0];   // [32][1024][1024]
  const int* ys         = (const int*)d_in[1];     // [32][1024]
  const float* masks    = (const float*)d_in[2];   // [32][1024]
  const float* fc_w     = (const float*)d_in[3];   // [1024][66]
  const float* fc_b     = (const float*)d_in[4];   // [66]
  const float* trans    = (const float*)d_in[5];   // [66][66]
  float* outp = (float*)d_out;                     // [0..31]=forward, [32..63]=gold

  // workspace layout
  char* ws = (char*)d_ws;
  float* feats_ws = (float*)ws;                                   // 8,388,608 B
  unsigned short* Wbt = (unsigned short*)(ws + 8388608);          //   131,072 B
  float* chunkP = (float*)(ws + 8388608 + 131072);                // 8,388,608 B
  int* chunkExp = (int*)(ws + 8388608 + 131072 + 8388608);        //     2,048 B

  crf_wcvt<<<256, 256, 0, stream>>>(fc_w, Wbt);
  dim3 cg(16, 32);
  crf_fwd<<<cg, 256, 0, stream>>>(features, Wbt, fc_b, masks, trans,
                                  feats_ws, chunkP, chunkExp);
  crf_fin<<<64, 64, 0, stream>>>(feats_ws, ys, masks, trans, chunkP, chunkExp, outp);
}

// Round 4
// 274.848 us; speedup vs baseline: 2.9629x; 1.0402x over previous
//
#include <hip/hip_runtime.h>
#include <hip/hip_bf16.h>
#include <stdint.h>

// CRF loss (forward partition + gold path score), B=32, L=1024, D=1024, 66 tags.
// Pipeline (3 kernels):
//   crf_wcvt : fc_w [1024][66] fp32 -> Wbt [64][1024] bf16 (LDS-tiled transpose)
//   crf_fwd  : per (chunk c, batch b) block:
//              (a) emission tile GEMM via bf16 MFMA with global_load_lds-staged
//                  A (fp32, XOR-swizzled via pre-swizzled source) and B (bf16),
//                  raw feats fp32 -> ws, exp(feats) -> LDS
//              (b) 64-step chunk product of M_t = diag(exp(emit_t)).E as
//                  64x64 bf16 MFMA matmuls with per-step pow2 rescale
//   crf_fin  : even blocks: per-batch combine (16 chained matvecs + STOP lse)
//              odd blocks:  gold path score (gathers)
//
// START/STOP tags are exact prob-0 (exp(-10000) underflows to 0 in f32, same
// as the reference) -> live state is exactly 64 tags = one wave lane each.

#define START_IDX 64
#define STOP_IDX 65
#define LN2F 0.6931471805599453f

typedef __attribute__((ext_vector_type(4))) float f32x4;
typedef __attribute__((ext_vector_type(8))) __bf16 bf16x8;
typedef __attribute__((ext_vector_type(4))) __bf16 bf16x4;

// async global->LDS, 16B per lane; dst = wave-uniform base + lane*16
__device__ __forceinline__ void gload_lds16(const void* g, void* l) {
  __builtin_amdgcn_global_load_lds(
      (const __attribute__((address_space(1))) void*)g,
      (__attribute__((address_space(3))) void*)l, 16, 0, 0);
}

// ------------------------------------------------------------------
// DPP helpers (full-wave reduce; result valid in lane 63; values >= 0)
// ------------------------------------------------------------------
template <int CTRL>
__device__ __forceinline__ float dpp_mov(float v) {
  return __int_as_float(
      __builtin_amdgcn_update_dpp(0, __float_as_int(v), CTRL, 0xF, 0xF, true));
}
__device__ __forceinline__ float wave_max64(float v) {
  v = fmaxf(v, dpp_mov<0xB1>(v));   // quad_perm xor1
  v = fmaxf(v, dpp_mov<0x4E>(v));   // quad_perm xor2
  v = fmaxf(v, dpp_mov<0x141>(v));  // row_half_mirror
  v = fmaxf(v, dpp_mov<0x140>(v));  // row_mirror
  v = fmaxf(v, dpp_mov<0x142>(v));  // row_bcast15
  v = fmaxf(v, dpp_mov<0x143>(v));  // row_bcast31
  return v;
}
__device__ __forceinline__ float wave_sum64(float v) {
  v += dpp_mov<0xB1>(v);
  v += dpp_mov<0x4E>(v);
  v += dpp_mov<0x141>(v);
  v += dpp_mov<0x140>(v);
  v += dpp_mov<0x142>(v);
  v += dpp_mov<0x143>(v);
  return v;
}

// ------------------------------------------------------------------
// W convert+transpose via LDS tile: Wbt[n][k] = bf16(W[k][n]), n<64, k<1024.
// Both global sides coalesced; LDS column read conflict-free (65-pad).
// ------------------------------------------------------------------
__global__ __launch_bounds__(256) void crf_wcvt(const float* __restrict__ W,
                                                unsigned short* __restrict__ Wbt) {
  __shared__ float tile[64][65];
  const int t = threadIdx.x;
  const int kb = blockIdx.x;  // k-slice of 64
#pragma unroll
  for (int i = 0; i < 16; ++i) {
    const int f = i * 256 + t;
    const int k = f >> 6, n = f & 63;
    tile[k][n] = W[(kb * 64 + k) * 66 + n];
  }
  __syncthreads();
#pragma unroll
  for (int i = 0; i < 16; ++i) {
    const int f = i * 256 + t;
    const int n = f >> 6, k = f & 63;
    union { __bf16 h; unsigned short u; } cv;
    cv.h = (__bf16)tile[k][n];
    Wbt[n * 1024 + kb * 64 + k] = cv.u;
  }
}

// ------------------------------------------------------------------
// Fused emission + chunk-product kernel. Grid (16 chunks, 32 batches), 4 waves.
// ------------------------------------------------------------------
__global__ __launch_bounds__(256) void crf_fwd(const float* __restrict__ features,
                                               const unsigned short* __restrict__ Wbt,
                                               const float* __restrict__ bias,
                                               const float* __restrict__ masks,
                                               const float* __restrict__ trans,
                                               float* __restrict__ featsOut,
                                               float* __restrict__ chunkP,
                                               int* __restrict__ chunkExp) {
  __shared__ __align__(16) float As[4096];            // 64 rows x 64 k fp32, swizzled
  __shared__ __align__(16) unsigned short Bs[4096];   // 64 tags x 64 k bf16, swizzled
  __shared__ __align__(16) float expE[64][64];        // exp(emissions) tile
  __shared__ __align__(16) unsigned short T[2][4096]; // P^T bf16, swizzled
  __shared__ float wmax[2][4];
  const int tid = threadIdx.x;
  const int w = tid >> 6, lane = tid & 63, g = lane >> 4, q = lane & 15;
  const int c = blockIdx.x, b = blockIdx.y;

  // ---- T[0] = identity (swizzled), wmax[0] = 1 ----
  {
    f32x4 z4 = {0.f, 0.f, 0.f, 0.f};
    *(f32x4*)((char*)T[0] + tid * 16) = z4;   // zero 4KB; 256x16B
    *(f32x4*)((char*)T[0] + 4096 + tid * 16) = z4;
    __syncthreads();
    if (tid < 64) {
      const int off = tid * 128 + ((2 * tid) ^ ((tid & 7) << 4));
      *(unsigned short*)((char*)T[0] + off) = (unsigned short)0x3F80;
    }
    if (tid < 4) wmax[0][tid] = 1.0f;
  }

  // ---- (a) emission tile GEMM: rows t = c*64 + [0,64), cols = 64 tags ----
  {
    const float* Abase = features + ((size_t)b << 20) + ((size_t)(c << 6) << 10);
    f32x4 acc[4];
#pragma unroll
    for (int nt = 0; nt < 4; ++nt) acc[nt] = (f32x4){0.f, 0.f, 0.f, 0.f};

    const int sA = (q & 7) << 4;           // A-frag swizzle (row = 16w+q)
    for (int k0 = 0; k0 < 1024; k0 += 64) {
      // stage A: wave w covers rows 16w..16w+16, 4 rows per issue
#pragma unroll
      for (int j = 0; j < 4; ++j) {
        const int row = 16 * w + 4 * j + (lane >> 4);
        const int colb = ((lane & 15) * 16) ^ ((row & 7) << 4);
        gload_lds16((const char*)(Abase + (size_t)row * 1024 + k0) + colb,
                    (char*)As + (16 * w + 4 * j) * 256);
      }
      // stage B: wave w covers tag-rows 16w..16w+16, 8 rows per issue
#pragma unroll
      for (int j = 0; j < 2; ++j) {
        const int n = 16 * w + 8 * j + (lane >> 3);
        const int colb = ((lane & 7) * 16) ^ ((n & 7) << 4);
        gload_lds16((const char*)(Wbt + (size_t)n * 1024 + k0) + colb,
                    (char*)Bs + (16 * w + 8 * j) * 128);
      }
      __syncthreads();  // drains vmcnt
#pragma unroll
      for (int kk = 0; kk < 64; kk += 32) {
        const char* Ab = (const char*)As + (16 * w + q) * 256;
        float4 alo = *(const float4*)(Ab + ((kk * 4 + 32 * g) ^ sA));
        float4 ahi = *(const float4*)(Ab + ((kk * 4 + 32 * g + 16) ^ sA));
        bf16x8 af;
        af[0] = (__bf16)alo.x; af[1] = (__bf16)alo.y;
        af[2] = (__bf16)alo.z; af[3] = (__bf16)alo.w;
        af[4] = (__bf16)ahi.x; af[5] = (__bf16)ahi.y;
        af[6] = (__bf16)ahi.z; af[7] = (__bf16)ahi.w;
#pragma unroll
        for (int nt = 0; nt < 4; ++nt) {
          const int n = q + 16 * nt;
          bf16x8 bf = *(const bf16x8*)((const char*)Bs + n * 128 +
                                       ((kk * 2 + 16 * g) ^ ((n & 7) << 4)));
          acc[nt] = __builtin_amdgcn_mfma_f32_16x16x32_bf16(af, bf, acc[nt], 0, 0, 0);
        }
      }
      __syncthreads();  // protect As/Bs before next stage
    }
    const float bb0 = bias[q + 0], bb1 = bias[q + 16];
    const float bb2 = bias[q + 32], bb3 = bias[q + 48];
#pragma unroll
    for (int r = 0; r < 4; ++r) {
      const int tl = 16 * w + 4 * g + r;  // C row (local t)
      float* orow = featsOut + (((size_t)(b << 10) + (c << 6) + tl) << 6) + q;
      const float v0 = acc[0][r] + bb0, v1 = acc[1][r] + bb1;
      const float v2 = acc[2][r] + bb2, v3 = acc[3][r] + bb3;
      orow[0] = v0; orow[16] = v1; orow[32] = v2; orow[48] = v3;
      expE[tl][q + 0]  = __expf(v0);
      expE[tl][q + 16] = __expf(v1);
      expE[tl][q + 32] = __expf(v2);
      expE[tl][q + 48] = __expf(v3);
    }
  }

  // ---- (b) chunk scan ----
  bf16x8 Ea0, Ea1;  // E fragments (A operand): rows i = 16w+q
  {
    const int i = 16 * w + q;
    const float* tp0 = trans + i * 66 + 8 * g;
    const float* tp1 = tp0 + 32;
#pragma unroll
    for (int e = 0; e < 8; ++e) {
      Ea0[e] = (__bf16)__expf(tp0[e]);
      Ea1[e] = (__bf16)__expf(tp1[e]);
    }
  }

  float pv[4][4];  // fp32 copy of P: row 16w+4g+r, col q+16nt
#pragma unroll
  for (int nt = 0; nt < 4; ++nt)
#pragma unroll
    for (int r = 0; r < 4; ++r)
      pv[nt][r] = ((16 * w + 4 * g + r) == (q + 16 * nt)) ? 1.f : 0.f;

  const int t0 = (c == 0) ? 1 : (c << 6);
  const int t1 = (c << 6) + 64;
  const float* mb = masks + (b << 10);
  const int tml = t0 + lane;
  const float mkv = mb[tml > 1023 ? 1023 : tml];

  int e_acc = 0;
  int cur = 0;
  __syncthreads();  // T[0], expE ready

  for (int t = t0; t < t1; ++t) {
    const int tl = t - (c << 6);
    const float4 ee = *(const float4*)&expE[tl][16 * w + 4 * g];  // exp(emit_t)
    const float m =
        __int_as_float(__builtin_amdgcn_readlane(__float_as_int(mkv), t - t0));
    if (m != 0.f) {
      const char* Tb = (const char*)T[cur];
      f32x4 acc[4];
#pragma unroll
      for (int nt = 0; nt < 4; ++nt) {
        const int n = q + 16 * nt;
        const int sw = (n & 7) << 4;
        bf16x8 B0 = *(const bf16x8*)(Tb + n * 128 + ((16 * g) ^ sw));
        bf16x8 B1 = *(const bf16x8*)(Tb + n * 128 + ((64 + 16 * g) ^ sw));
        f32x4 z = {0.f, 0.f, 0.f, 0.f};
        z = __builtin_amdgcn_mfma_f32_16x16x32_bf16(Ea0, B0, z, 0, 0, 0);
        acc[nt] = __builtin_amdgcn_mfma_f32_16x16x32_bf16(Ea1, B1, z, 0, 0, 0);
      }
      const float4 wm = *(const float4*)wmax[cur];
      const float mx = fmaxf(fmaxf(wm.x, wm.y), fmaxf(wm.z, wm.w));
      const int ex = ((__float_as_int(mx) >> 23) & 0xFF) - 127;
      const float sc = __int_as_float((127 - ex) << 23);
      float ce[4];
      ce[0] = ee.x * sc; ce[1] = ee.y * sc; ce[2] = ee.z * sc; ce[3] = ee.w * sc;
      float lm = 0.f;
#pragma unroll
      for (int nt = 0; nt < 4; ++nt) {
#pragma unroll
        for (int r = 0; r < 4; ++r) {
          float val = acc[nt][r] * ce[r];
          if (m != 1.f) val = m * val + (1.f - m) * sc * pv[nt][r];
          pv[nt][r] = val;
          lm = fmaxf(lm, val);
        }
      }
      lm = wave_max64(lm);
      const int nxt = cur ^ 1;
      char* Tw = (char*)T[nxt];
#pragma unroll
      for (int nt = 0; nt < 4; ++nt) {
        bf16x4 o;
        o[0] = (__bf16)pv[nt][0]; o[1] = (__bf16)pv[nt][1];
        o[2] = (__bf16)pv[nt][2]; o[3] = (__bf16)pv[nt][3];
        const int n = q + 16 * nt;
        *(bf16x4*)(Tw + n * 128 + ((32 * w + 8 * g) ^ ((n & 7) << 4))) = o;
      }
      if (lane == 63) wmax[nxt][w] = lm;
      e_acc += ex;
      __syncthreads();
      cur = nxt;
    }
  }

  // epilogue: write P (fp32) + exponent
#pragma unroll
  for (int nt = 0; nt < 4; ++nt)
#pragma unroll
    for (int r = 0; r < 4; ++r)
      chunkP[(((size_t)(b * 16 + c)) << 12) + (size_t)(16 * w + 4 * g + r) * 64 +
             q + 16 * nt] = pv[nt][r];
  if (tid == 0) chunkExp[b * 16 + c] = e_acc;
}

// ------------------------------------------------------------------
// Final kernel: even blocks -> combine (forward score), odd -> gold score.
// ------------------------------------------------------------------
__global__ void crf_fin(const float* __restrict__ feats,
                        const int* __restrict__ ys,
                        const float* __restrict__ masks,
                        const float* __restrict__ trans,
                        const float* __restrict__ chunkP,
                        const int* __restrict__ chunkExp,
                        float* __restrict__ out) {
  __shared__ __align__(16) float vb[64];
  const int lane = threadIdx.x;
  const int b = blockIdx.x >> 1;
  if ((blockIdx.x & 1) == 0) {
    // ---- combine: v <- Pc . v over 16 chunks, then STOP logsumexp ----
    float v = __expf(feats[((size_t)b << 16) + lane]) *
              __expf(trans[lane * 66 + START_IDX]);
    int e_acc = 0;
    for (int cc = 0; cc < 16; ++cc) {
      vb[lane] = v;
      __builtin_amdgcn_wave_barrier();
      const float* Pr = chunkP + (((size_t)(b * 16 + cc)) << 12) + (size_t)lane * 64;
      float q0 = 0.f, q1 = 0.f, q2 = 0.f, q3 = 0.f;
#pragma unroll
      for (int j4 = 0; j4 < 16; ++j4) {
        float4 p = *(const float4*)(Pr + 4 * j4);
        float4 x = ((const float4*)vb)[j4];
        q0 = fmaf(p.x, x.x, q0); q1 = fmaf(p.y, x.y, q1);
        q2 = fmaf(p.z, x.z, q2); q3 = fmaf(p.w, x.w, q3);
      }
      const float qq = (q0 + q1) + (q2 + q3);
      float mx = wave_max64(qq);
      mx = __int_as_float(__builtin_amdgcn_readlane(__float_as_int(mx), 63));
      const int ex = ((__float_as_int(mx) >> 23) & 0xFF) - 127;
      v = qq * __int_as_float((127 - ex) << 23);
      e_acc += ex + chunkExp[b * 16 + cc];
      __builtin_amdgcn_wave_barrier();
    }
    const float sum = wave_sum64(v * __expf(trans[STOP_IDX * 66 + lane]));
    const float s =
        __int_as_float(__builtin_amdgcn_readlane(__float_as_int(sum), 63));
    if (lane == 0) out[b] = __logf(s) + (float)e_acc * LN2F;
  } else {
    // ---- gold path score ----
    const float* fb = feats + ((size_t)b << 16);
    const float* mb = masks + (b << 10);
    const int* yb = ys + (b << 10);
    float s = 0.f, cnt = 0.f;
#pragma unroll
    for (int cc = 0; cc < 16; ++cc) {
      const int t = cc * 64 + lane;
      const float m = mb[t];
      const int y = yb[t];
      const int yp = (t == 0) ? START_IDX : yb[t - 1];
      s += (trans[y * 66 + yp] + fb[t * 64 + y]) * m;
      cnt += m;
    }
    float tot = wave_sum64(s);
    float len = wave_sum64(cnt);
    int totb = __builtin_amdgcn_readlane(__float_as_int(tot), 63);
    int lenb = __builtin_amdgcn_readlane(__float_as_int(len), 63);
    if (lane == 0) {
      const int Lr = (int)__int_as_float(lenb);
      const int last = (Lr == 0) ? START_IDX : yb[Lr - 1];
      out[32 + b] = __int_as_float(totb) + trans[STOP_IDX * 66 + last];
    }
  }
}

// ------------------------------------------------------------------
extern "C" void kernel_launch(void* const* d_in, const int* in_sizes, int n_in,
                              void* d_out, int out_size, void* d_ws, size_t ws_size,
                              hipStream_t stream) {
  const float* features = (const float*)d_in[0];   // [32][1024][1024]
  const int* ys         = (const int*)d_in[1];     // [32][1024]
  const float* masks    = (const float*)d_in[2];   // [32][1024]
  const float* fc_w     = (const float*)d_in[3];   // [1024][66]
  const float* fc_b     = (const float*)d_in[4];   // [66]
  const float* trans    = (const float*)d_in[5];   // [66][66]
  float* outp = (float*)d_out;                     // [0..31]=forward, [32..63]=gold

  // workspace layout
  char* ws = (char*)d_ws;
  float* feats_ws = (float*)ws;                                   // 8,388,608 B
  unsigned short* Wbt = (unsigned short*)(ws + 8388608);          //   131,072 B
  float* chunkP = (float*)(ws + 8388608 + 131072);                // 8,388,608 B
  int* chunkExp = (int*)(ws + 8388608 + 131072 + 8388608);        //     2,048 B

  crf_wcvt<<<16, 256, 0, stream>>>(fc_w, Wbt);
  dim3 cg(16, 32);
  crf_fwd<<<cg, 256, 0, stream>>>(features, Wbt, fc_b, masks, trans,
                                  feats_ws, chunkP, chunkExp);
  crf_fin<<<64, 64, 0, stream>>>(feats_ws, ys, masks, trans, chunkP, chunkExp, outp);
}